// Round 5
// baseline (167.287 us; speedup 1.0000x reference)
//
#include <hip/hip_runtime.h>

#define EDGE_BLOCKS  512
#define EDGE_THREADS 1024
#define PACK_WORDS_MAX 12512   // 50,048 B LDS table -> supports n_nodes <= 100,096

// ws layout (bytes):
//   [0, 24)                     : 3 x u64 adjacency masks (bit p = src*12+dst)
//   [128, 132)                  : u32 ticket (zeroed by pack_classes each launch)
//   [256, 256+EDGE_BLOCKS*4)    : per-block float partials
//   [8192, 8192+4*n_words)      : packed 4-bit node-class table
#define WS_MASK_OFF    0
#define WS_TICKET_OFF  128
#define WS_PART_OFF    256
#define WS_PACK_OFF    8192

#define LOG2E 1.44269504088896f
#define LN2   0.69314718055995f

// ---------- kernel A: pack node classes to nibbles + masks + zero ticket ----------
__global__ void pack_classes(const int* __restrict__ node_classes,
                             const float* __restrict__ adj,
                             unsigned* __restrict__ packed,
                             unsigned* __restrict__ masks,   // 6 x u32 halves
                             unsigned* __restrict__ ticket,
                             int n_nodes, int n_words)
{
    int w = blockIdx.x * blockDim.x + threadIdx.x;
    if (w < n_words) {
        unsigned v = 0;
        int base = w << 3;
        #pragma unroll
        for (int j = 0; j < 8; ++j) {
            int n = base + j;
            unsigned c = (n < n_nodes) ? (unsigned)node_classes[n] : 0u;
            v |= (c & 0xFu) << (4 * j);
        }
        packed[w] = v;
    }
    if (w == 0) {
        unsigned h[5] = {0, 0, 0, 0, 0};
        for (int p = 0; p < 144; ++p)
            if (adj[p] > 0.5f) h[p >> 5] |= (1u << (p & 31));
        #pragma unroll
        for (int i = 0; i < 5; ++i) masks[i] = h[i];
        masks[5] = 0u;
        *ticket = 0u;
    }
}

// ---------- kernel B: edge loss, LDS class table, fused final reduce ----------
__global__ __launch_bounds__(EDGE_THREADS, 8) void edge_loss_lds(
    const unsigned* __restrict__ packed_g,
    const unsigned* __restrict__ masks_g,
    unsigned*       __restrict__ ticket,
    const float* __restrict__ edge_scores,
    const int*   __restrict__ edge_src,
    const int*   __restrict__ edge_dst,
    float*       __restrict__ partial,
    float*       __restrict__ out,
    int n_edges, int n_words, float inv_n)
{
    __shared__ unsigned s_packed[PACK_WORDS_MAX]; // 50,048 B
    __shared__ float    s_wsum[EDGE_THREADS / 64];
    __shared__ double   s_dsum[8];
    __shared__ int      s_last;

    const int tid = threadIdx.x;

    // Stage packed table, 16B chunks.
    {
        int nv = n_words >> 2;
        const uint4* p4 = (const uint4*)packed_g;
        for (int i = tid; i < nv; i += EDGE_THREADS) {
            uint4 v = p4[i];
            s_packed[4*i+0] = v.x; s_packed[4*i+1] = v.y;
            s_packed[4*i+2] = v.z; s_packed[4*i+3] = v.w;
        }
        for (int i = (nv << 2) + tid; i < n_words; i += EDGE_THREADS)
            s_packed[i] = packed_g[i];
    }
    // Uniform mask halves -> scalar regs.
    const unsigned h0 = masks_g[0], h1 = masks_g[1], h2 = masks_g[2];
    const unsigned h3 = masks_g[3], h4 = masks_g[4];
    __syncthreads();

    const int gtid   = blockIdx.x * EDGE_THREADS + tid;
    const int stride = gridDim.x * EDGE_THREADS;
    const int ngrp   = n_edges >> 2;

    const int4*   srcv = (const int4*)  edge_src;
    const int4*   dstv = (const int4*)  edge_dst;
    const float4* scov = (const float4*)edge_scores;

    float acc_a = 0.0f;
    float acc_l = 0.0f;

    for (int g = gtid; g < ngrp; g += stride) {
        const int4   si = srcv[g];
        const int4   di = dstv[g];
        const float4 sc = scov[g];

        unsigned wa0 = s_packed[si.x >> 3], wa1 = s_packed[si.y >> 3];
        unsigned wa2 = s_packed[si.z >> 3], wa3 = s_packed[si.w >> 3];
        unsigned wb0 = s_packed[di.x >> 3], wb1 = s_packed[di.y >> 3];
        unsigned wb2 = s_packed[di.z >> 3], wb3 = s_packed[di.w >> 3];

        int a0 = (wa0 >> ((si.x & 7) << 2)) & 0xF;
        int a1 = (wa1 >> ((si.y & 7) << 2)) & 0xF;
        int a2 = (wa2 >> ((si.z & 7) << 2)) & 0xF;
        int a3 = (wa3 >> ((si.w & 7) << 2)) & 0xF;
        int b0 = (wb0 >> ((di.x & 7) << 2)) & 0xF;
        int b1 = (wb1 >> ((di.y & 7) << 2)) & 0xF;
        int b2 = (wb2 >> ((di.z & 7) << 2)) & 0xF;
        int b3 = (wb3 >> ((di.w & 7) << 2)) & 0xF;

        // y from register mask halves: p = a*12+b in [0,144)
        #define Y_OF(a_, b_, y_) {                                   \
            int p = a_ * 12 + b_;                                    \
            unsigned s01 = (p & 32) ? h1 : h0;                       \
            unsigned s23 = (p & 32) ? h3 : h2;                       \
            unsigned sel = (p & 64) ? s23 : s01;                     \
            sel = (p & 128) ? h4 : sel;                              \
            y_ = (sel >> (p & 31)) & 1u;                             \
        }
        unsigned y0, y1, y2, y3;
        Y_OF(a0, b0, y0); Y_OF(a1, b1, y1);
        Y_OF(a2, b2, y2); Y_OF(a3, b3, y3);
        #undef Y_OF

        float s0 = sc.x, s1 = sc.y, s2 = sc.z, s3 = sc.w;

        float t0 = __builtin_amdgcn_exp2f(-fabsf(s0) * LOG2E);
        float t1 = __builtin_amdgcn_exp2f(-fabsf(s1) * LOG2E);
        float t2 = __builtin_amdgcn_exp2f(-fabsf(s2) * LOG2E);
        float t3 = __builtin_amdgcn_exp2f(-fabsf(s3) * LOG2E);

        acc_a += fmaxf(s0, 0.0f) - (y0 ? s0 : 0.0f);
        acc_a += fmaxf(s1, 0.0f) - (y1 ? s1 : 0.0f);
        acc_a += fmaxf(s2, 0.0f) - (y2 ? s2 : 0.0f);
        acc_a += fmaxf(s3, 0.0f) - (y3 ? s3 : 0.0f);

        acc_l += __builtin_amdgcn_logf(1.0f + t0);
        acc_l += __builtin_amdgcn_logf(1.0f + t1);
        acc_l += __builtin_amdgcn_logf(1.0f + t2);
        acc_l += __builtin_amdgcn_logf(1.0f + t3);
    }

    // scalar tail
    for (int e = (ngrp << 2) + gtid; e < n_edges; e += stride) {
        int n = edge_src[e], m = edge_dst[e];
        int a = (s_packed[n >> 3] >> ((n & 7) << 2)) & 0xF;
        int b = (s_packed[m >> 3] >> ((m & 7) << 2)) & 0xF;
        int p = a * 12 + b;
        unsigned s01 = (p & 32) ? h1 : h0;
        unsigned s23 = (p & 32) ? h3 : h2;
        unsigned sel = (p & 64) ? s23 : s01;
        sel = (p & 128) ? h4 : sel;
        unsigned y = (sel >> (p & 31)) & 1u;
        float s = edge_scores[e];
        float t = __builtin_amdgcn_exp2f(-fabsf(s) * LOG2E);
        acc_a += fmaxf(s, 0.0f) - (y ? s : 0.0f);
        acc_l += __builtin_amdgcn_logf(1.0f + t);
    }

    float acc = fmaf(LN2, acc_l, acc_a);

    #pragma unroll
    for (int off = 32; off > 0; off >>= 1)
        acc += __shfl_down(acc, off, 64);

    const int wave = tid >> 6;
    const int lane = tid & 63;
    if (lane == 0) s_wsum[wave] = acc;
    __syncthreads();

    if (tid == 0) {
        float b = 0.0f;
        #pragma unroll
        for (int w = 0; w < EDGE_THREADS / 64; ++w) b += s_wsum[w];
        partial[blockIdx.x] = b;
        __threadfence();   // make partial visible device-wide before ticket
        unsigned t = __hip_atomic_fetch_add(ticket, 1u, __ATOMIC_ACQ_REL,
                                            __HIP_MEMORY_SCOPE_AGENT);
        s_last = (t == (unsigned)(gridDim.x - 1)) ? 1 : 0;
    }
    __syncthreads();

    if (s_last) {
        // Last block: deterministic reduce of all block partials.
        const int nblk = gridDim.x;   // 512
        double d = 0.0;
        for (int i = tid; i < nblk; i += EDGE_THREADS) {
            float v = __hip_atomic_load(&partial[i], __ATOMIC_RELAXED,
                                        __HIP_MEMORY_SCOPE_AGENT);
            d += (double)v;
        }
        #pragma unroll
        for (int off = 32; off > 0; off >>= 1)
            d += __shfl_down(d, off, 64);
        if (lane == 0) s_dsum[wave] = d;
        __syncthreads();
        if (tid == 0) {
            double tsum = 0.0;
            #pragma unroll
            for (int w = 0; w < EDGE_THREADS / 64; ++w) tsum += s_dsum[w];
            out[0] = (float)(tsum * (double)inv_n);
        }
    }
}

// ---------- fallback path ----------
__global__ __launch_bounds__(256) void edge_loss_fallback(
    const int*   __restrict__ node_classes,
    const float* __restrict__ edge_scores,
    const int*   __restrict__ edge_src,
    const int*   __restrict__ edge_dst,
    const float* __restrict__ adj,
    float*       __restrict__ partial,
    int n_edges)
{
    __shared__ unsigned s_mask[16];
    const int tid = threadIdx.x;
    if (tid < 12) {
        unsigned m = 0u;
        for (int j = 0; j < 12; ++j)
            if (adj[tid * 12 + j] > 0.5f) m |= (1u << j);
        s_mask[tid] = m;
    }
    __syncthreads();
    const int gtid   = blockIdx.x * 256 + tid;
    const int stride = gridDim.x * 256;
    float acc = 0.0f;
    for (int e = gtid; e < n_edges; e += stride) {
        int a = node_classes[edge_src[e]];
        int b = node_classes[edge_dst[e]];
        float y = (float)((s_mask[a] >> b) & 1u);
        float s = edge_scores[e];
        float t = __builtin_amdgcn_exp2f(-fabsf(s) * LOG2E);
        acc += fmaxf(s, 0.0f) - s * y + LN2 * __builtin_amdgcn_logf(1.0f + t);
    }
    #pragma unroll
    for (int off = 32; off > 0; off >>= 1)
        acc += __shfl_down(acc, off, 64);
    __shared__ float s_wsum[4];
    const int wave = tid >> 6, lane = tid & 63;
    if (lane == 0) s_wsum[wave] = acc;
    __syncthreads();
    if (tid == 0) {
        float b = 0.0f;
        for (int w = 0; w < 4; ++w) b += s_wsum[w];
        partial[blockIdx.x] = b;
    }
}

__global__ __launch_bounds__(256) void final_reduce(
    const float* __restrict__ partial,
    float*       __restrict__ out,
    int nblk, float inv_n)
{
    const int tid = threadIdx.x;
    double acc = 0.0;
    for (int i = tid; i < nblk; i += 256) acc += (double)partial[i];
    #pragma unroll
    for (int off = 32; off > 0; off >>= 1)
        acc += __shfl_down(acc, off, 64);
    __shared__ double s_wsum[4];
    const int wave = tid >> 6, lane = tid & 63;
    if (lane == 0) s_wsum[wave] = acc;
    __syncthreads();
    if (tid == 0) {
        double t = s_wsum[0] + s_wsum[1] + s_wsum[2] + s_wsum[3];
        out[0] = (float)(t * (double)inv_n);
    }
}

extern "C" void kernel_launch(void* const* d_in, const int* in_sizes, int n_in,
                              void* d_out, int out_size, void* d_ws, size_t ws_size,
                              hipStream_t stream) {
    const int*   node_classes = (const int*)  d_in[0];
    const float* edge_scores  = (const float*)d_in[1];
    const int*   edge_indices = (const int*)  d_in[2];
    const float* adj          = (const float*)d_in[3];

    const int n_nodes = in_sizes[0];
    const int n_edges = in_sizes[1];
    const int n_words = (n_nodes + 7) >> 3;

    const int* edge_src = edge_indices;
    const int* edge_dst = edge_indices + n_edges;

    char* ws = (char*)d_ws;
    unsigned* masks   = (unsigned*)(ws + WS_MASK_OFF);
    unsigned* ticket  = (unsigned*)(ws + WS_TICKET_OFF);
    float*    partial = (float*)   (ws + WS_PART_OFF);
    unsigned* packed  = (unsigned*)(ws + WS_PACK_OFF);
    float* out = (float*)d_out;

    const size_t needed = (size_t)WS_PACK_OFF + (size_t)n_words * 4u;

    if (ws_size >= needed && n_words <= PACK_WORDS_MAX) {
        int pack_blocks = (n_words + 255) / 256;
        pack_classes<<<pack_blocks, 256, 0, stream>>>(
            node_classes, adj, packed, masks, ticket, n_nodes, n_words);
        edge_loss_lds<<<EDGE_BLOCKS, EDGE_THREADS, 0, stream>>>(
            packed, masks, ticket, edge_scores, edge_src, edge_dst,
            partial, out, n_edges, n_words, 1.0f / (float)n_edges);
    } else {
        edge_loss_fallback<<<2048, 256, 0, stream>>>(
            node_classes, edge_scores, edge_src, edge_dst, adj, partial, n_edges);
        final_reduce<<<1, 256, 0, stream>>>(partial, out, 2048,
                                            1.0f / (float)n_edges);
    }
}

// Round 6
// 157.048 us; speedup vs baseline: 1.0652x; 1.0652x over previous
//
#include <hip/hip_runtime.h>

#define EDGE_BLOCKS  512
#define EDGE_THREADS 1024
#define PACK_WORDS_MAX 12512   // 50,048 B LDS table -> supports n_nodes <= 100,096

// ws layout (bytes):
//   [128, 132)                  : u32 ticket (zeroed by pack_classes each launch)
//   [256, 256+EDGE_BLOCKS*4)    : per-block float partials
//   [8192, 8192+4*n_words)      : packed 4-bit node-class table
#define WS_TICKET_OFF  128
#define WS_PART_OFF    256
#define WS_PACK_OFF    8192

#define LOG2E 1.44269504088896f
#define LN2   0.69314718055995f

// ---------- kernel A: pack node classes to nibbles + zero ticket ----------
__global__ void pack_classes(const int* __restrict__ node_classes,
                             unsigned* __restrict__ packed,
                             unsigned* __restrict__ ticket,
                             int n_nodes, int n_words)
{
    int w = blockIdx.x * blockDim.x + threadIdx.x;
    if (w < n_words) {
        unsigned v = 0;
        int base = w << 3;
        #pragma unroll
        for (int j = 0; j < 8; ++j) {
            int n = base + j;
            unsigned c = (n < n_nodes) ? (unsigned)node_classes[n] : 0u;
            v |= (c & 0xFu) << (4 * j);
        }
        packed[w] = v;
    }
    if (w == 0) *ticket = 0u;
}

// ---------- kernel B: R4 loop (explicit pipeline + s_mask LDS) + fused reduce ----------
__global__ __launch_bounds__(EDGE_THREADS, 8) void edge_loss_lds(
    const unsigned* __restrict__ packed_g,
    unsigned*       __restrict__ ticket,
    const float* __restrict__ edge_scores,
    const int*   __restrict__ edge_src,
    const int*   __restrict__ edge_dst,
    const float* __restrict__ adj,
    float*       __restrict__ partial,
    float*       __restrict__ out,
    int n_edges, int n_words, float inv_n)
{
    __shared__ unsigned s_packed[PACK_WORDS_MAX]; // 50,048 B
    __shared__ unsigned s_mask[16];
    __shared__ float    s_wsum[EDGE_THREADS / 64];
    __shared__ double   s_dsum[EDGE_THREADS / 64];
    __shared__ int      s_last;

    const int tid = threadIdx.x;

    if (tid < 16) {
        unsigned m = 0u;
        if (tid < 12) {
            #pragma unroll
            for (int j = 0; j < 12; ++j)
                if (adj[tid * 12 + j] > 0.5f) m |= (1u << j);
        }
        s_mask[tid] = m;
    }
    {
        int nv = n_words >> 2;
        const uint4* p4 = (const uint4*)packed_g;
        for (int i = tid; i < nv; i += EDGE_THREADS) {
            uint4 v = p4[i];
            s_packed[4*i+0] = v.x; s_packed[4*i+1] = v.y;
            s_packed[4*i+2] = v.z; s_packed[4*i+3] = v.w;
        }
        for (int i = (nv << 2) + tid; i < n_words; i += EDGE_THREADS)
            s_packed[i] = packed_g[i];
    }
    __syncthreads();

    const int gtid   = blockIdx.x * EDGE_THREADS + tid;
    const int stride = gridDim.x * EDGE_THREADS;
    const int ngrp   = n_edges >> 2;

    const int4*   srcv = (const int4*)  edge_src;
    const int4*   dstv = (const int4*)  edge_dst;
    const float4* scov = (const float4*)edge_scores;

    float acc_a = 0.0f;   // max(s,0) - y*s terms
    float acc_l = 0.0f;   // log2-domain terms (scale by LN2 at end)

    int g = gtid;
    if (g < ngrp) {
        // explicit 2-deep pipeline: keeps VGPR allocation rich so all three
        // 16B loads of a trip stay in flight (R5 showed the allocator
        // otherwise collapses to 24 VGPRs and serializes: 22us -> 66us).
        int4   si = srcv[g];
        int4   di = dstv[g];
        float4 sc = scov[g];

        while (true) {
            const int gn = g + stride;
            int4 si_n, di_n; float4 sc_n;
            const bool more = (gn < ngrp);
            if (more) {
                si_n = srcv[gn];
                di_n = dstv[gn];
                sc_n = scov[gn];
            }

            unsigned wa0 = s_packed[si.x >> 3], wa1 = s_packed[si.y >> 3];
            unsigned wa2 = s_packed[si.z >> 3], wa3 = s_packed[si.w >> 3];
            unsigned wb0 = s_packed[di.x >> 3], wb1 = s_packed[di.y >> 3];
            unsigned wb2 = s_packed[di.z >> 3], wb3 = s_packed[di.w >> 3];

            int a0 = (wa0 >> ((si.x & 7) << 2)) & 0xF;
            int a1 = (wa1 >> ((si.y & 7) << 2)) & 0xF;
            int a2 = (wa2 >> ((si.z & 7) << 2)) & 0xF;
            int a3 = (wa3 >> ((si.w & 7) << 2)) & 0xF;
            int b0 = (wb0 >> ((di.x & 7) << 2)) & 0xF;
            int b1 = (wb1 >> ((di.y & 7) << 2)) & 0xF;
            int b2 = (wb2 >> ((di.z & 7) << 2)) & 0xF;
            int b3 = (wb3 >> ((di.w & 7) << 2)) & 0xF;

            unsigned y0 = (s_mask[a0] >> b0) & 1u;
            unsigned y1 = (s_mask[a1] >> b1) & 1u;
            unsigned y2 = (s_mask[a2] >> b2) & 1u;
            unsigned y3 = (s_mask[a3] >> b3) & 1u;

            float s0 = sc.x, s1 = sc.y, s2 = sc.z, s3 = sc.w;

            float t0 = __builtin_amdgcn_exp2f(-fabsf(s0) * LOG2E);
            float t1 = __builtin_amdgcn_exp2f(-fabsf(s1) * LOG2E);
            float t2 = __builtin_amdgcn_exp2f(-fabsf(s2) * LOG2E);
            float t3 = __builtin_amdgcn_exp2f(-fabsf(s3) * LOG2E);

            acc_a += fmaxf(s0, 0.0f) - (y0 ? s0 : 0.0f);
            acc_a += fmaxf(s1, 0.0f) - (y1 ? s1 : 0.0f);
            acc_a += fmaxf(s2, 0.0f) - (y2 ? s2 : 0.0f);
            acc_a += fmaxf(s3, 0.0f) - (y3 ? s3 : 0.0f);

            acc_l += __builtin_amdgcn_logf(1.0f + t0);
            acc_l += __builtin_amdgcn_logf(1.0f + t1);
            acc_l += __builtin_amdgcn_logf(1.0f + t2);
            acc_l += __builtin_amdgcn_logf(1.0f + t3);

            if (!more) break;
            si = si_n; di = di_n; sc = sc_n; g = gn;
        }
    }

    // scalar tail (n_edges not divisible by 4)
    for (int e = (ngrp << 2) + gtid; e < n_edges; e += stride) {
        int n = edge_src[e], m = edge_dst[e];
        int a = (s_packed[n >> 3] >> ((n & 7) << 2)) & 0xF;
        int b = (s_packed[m >> 3] >> ((m & 7) << 2)) & 0xF;
        unsigned y = (s_mask[a] >> b) & 1u;
        float s = edge_scores[e];
        float t = __builtin_amdgcn_exp2f(-fabsf(s) * LOG2E);
        acc_a += fmaxf(s, 0.0f) - (y ? s : 0.0f);
        acc_l += __builtin_amdgcn_logf(1.0f + t);
    }

    float acc = fmaf(LN2, acc_l, acc_a);

    #pragma unroll
    for (int off = 32; off > 0; off >>= 1)
        acc += __shfl_down(acc, off, 64);

    const int wave = tid >> 6;
    const int lane = tid & 63;
    if (lane == 0) s_wsum[wave] = acc;
    __syncthreads();

    if (tid == 0) {
        float b = 0.0f;
        #pragma unroll
        for (int w = 0; w < EDGE_THREADS / 64; ++w) b += s_wsum[w];
        partial[blockIdx.x] = b;
        __threadfence();   // partial visible device-wide before ticket bump
        unsigned t = __hip_atomic_fetch_add(ticket, 1u, __ATOMIC_ACQ_REL,
                                            __HIP_MEMORY_SCOPE_AGENT);
        s_last = (t == (unsigned)(gridDim.x - 1)) ? 1 : 0;
    }
    __syncthreads();

    if (s_last) {
        const int nblk = gridDim.x;   // 512
        double d = 0.0;
        for (int i = tid; i < nblk; i += EDGE_THREADS) {
            float v = __hip_atomic_load(&partial[i], __ATOMIC_RELAXED,
                                        __HIP_MEMORY_SCOPE_AGENT);
            d += (double)v;
        }
        #pragma unroll
        for (int off = 32; off > 0; off >>= 1)
            d += __shfl_down(d, off, 64);
        if (lane == 0) s_dsum[wave] = d;
        __syncthreads();
        if (tid == 0) {
            double tsum = 0.0;
            #pragma unroll
            for (int w = 0; w < EDGE_THREADS / 64; ++w) tsum += s_dsum[w];
            out[0] = (float)(tsum * (double)inv_n);
        }
    }
}

// ---------- fallback path ----------
__global__ __launch_bounds__(256) void edge_loss_fallback(
    const int*   __restrict__ node_classes,
    const float* __restrict__ edge_scores,
    const int*   __restrict__ edge_src,
    const int*   __restrict__ edge_dst,
    const float* __restrict__ adj,
    float*       __restrict__ partial,
    int n_edges)
{
    __shared__ unsigned s_mask[16];
    const int tid = threadIdx.x;
    if (tid < 12) {
        unsigned m = 0u;
        for (int j = 0; j < 12; ++j)
            if (adj[tid * 12 + j] > 0.5f) m |= (1u << j);
        s_mask[tid] = m;
    }
    __syncthreads();
    const int gtid   = blockIdx.x * 256 + tid;
    const int stride = gridDim.x * 256;
    float acc = 0.0f;
    for (int e = gtid; e < n_edges; e += stride) {
        int a = node_classes[edge_src[e]];
        int b = node_classes[edge_dst[e]];
        float y = (float)((s_mask[a] >> b) & 1u);
        float s = edge_scores[e];
        float t = __builtin_amdgcn_exp2f(-fabsf(s) * LOG2E);
        acc += fmaxf(s, 0.0f) - s * y + LN2 * __builtin_amdgcn_logf(1.0f + t);
    }
    #pragma unroll
    for (int off = 32; off > 0; off >>= 1)
        acc += __shfl_down(acc, off, 64);
    __shared__ float s_wsum[4];
    const int wave = tid >> 6, lane = tid & 63;
    if (lane == 0) s_wsum[wave] = acc;
    __syncthreads();
    if (tid == 0) {
        float b = 0.0f;
        for (int w = 0; w < 4; ++w) b += s_wsum[w];
        partial[blockIdx.x] = b;
    }
}

__global__ __launch_bounds__(256) void final_reduce(
    const float* __restrict__ partial,
    float*       __restrict__ out,
    int nblk, float inv_n)
{
    const int tid = threadIdx.x;
    double acc = 0.0;
    for (int i = tid; i < nblk; i += 256) acc += (double)partial[i];
    #pragma unroll
    for (int off = 32; off > 0; off >>= 1)
        acc += __shfl_down(acc, off, 64);
    __shared__ double s_wsum[4];
    const int wave = tid >> 6, lane = tid & 63;
    if (lane == 0) s_wsum[wave] = acc;
    __syncthreads();
    if (tid == 0) {
        double t = s_wsum[0] + s_wsum[1] + s_wsum[2] + s_wsum[3];
        out[0] = (float)(t * (double)inv_n);
    }
}

extern "C" void kernel_launch(void* const* d_in, const int* in_sizes, int n_in,
                              void* d_out, int out_size, void* d_ws, size_t ws_size,
                              hipStream_t stream) {
    const int*   node_classes = (const int*)  d_in[0];
    const float* edge_scores  = (const float*)d_in[1];
    const int*   edge_indices = (const int*)  d_in[2];
    const float* adj          = (const float*)d_in[3];

    const int n_nodes = in_sizes[0];
    const int n_edges = in_sizes[1];
    const int n_words = (n_nodes + 7) >> 3;

    const int* edge_src = edge_indices;
    const int* edge_dst = edge_indices + n_edges;

    char* ws = (char*)d_ws;
    unsigned* ticket  = (unsigned*)(ws + WS_TICKET_OFF);
    float*    partial = (float*)   (ws + WS_PART_OFF);
    unsigned* packed  = (unsigned*)(ws + WS_PACK_OFF);
    float* out = (float*)d_out;

    const size_t needed = (size_t)WS_PACK_OFF + (size_t)n_words * 4u;

    if (ws_size >= needed && n_words <= PACK_WORDS_MAX) {
        int pack_blocks = (n_words + 255) / 256;
        pack_classes<<<pack_blocks, 256, 0, stream>>>(
            node_classes, packed, ticket, n_nodes, n_words);
        edge_loss_lds<<<EDGE_BLOCKS, EDGE_THREADS, 0, stream>>>(
            packed, ticket, edge_scores, edge_src, edge_dst, adj,
            partial, out, n_edges, n_words, 1.0f / (float)n_edges);
    } else {
        edge_loss_fallback<<<2048, 256, 0, stream>>>(
            node_classes, edge_scores, edge_src, edge_dst, adj, partial, n_edges);
        final_reduce<<<1, 256, 0, stream>>>(partial, out, 2048,
                                            1.0f / (float)n_edges);
    }
}

// Round 7
// 121.962 us; speedup vs baseline: 1.3716x; 1.2877x over previous
//
#include <hip/hip_runtime.h>

#define EDGE_BLOCKS  512
#define EDGE_THREADS 1024
#define PACK_WORDS_MAX 12512   // 50,048 B LDS table -> supports n_nodes <= 100,096

// ws layout (bytes):
//   [256, 256+EDGE_BLOCKS*4)    : per-block float partials
//   [8192, 8192+4*n_words)      : packed 4-bit node-class table
#define WS_PART_OFF    256
#define WS_PACK_OFF    8192

#define LOG2E 1.44269504088896f
#define LN2   0.69314718055995f

// ---------- kernel A: pack node classes to nibbles ----------
__global__ void pack_classes(const int* __restrict__ node_classes,
                             unsigned* __restrict__ packed,
                             int n_nodes, int n_words)
{
    int w = blockIdx.x * blockDim.x + threadIdx.x;
    if (w < n_words) {
        unsigned v = 0;
        int base = w << 3;
        #pragma unroll
        for (int j = 0; j < 8; ++j) {
            int n = base + j;
            unsigned c = (n < n_nodes) ? (unsigned)node_classes[n] : 0u;
            v |= (c & 0xFu) << (4 * j);
        }
        packed[w] = v;
    }
}

// ---------- kernel B: edge loss, LDS class table, pipelined (R4-exact) ----------
// NOTE: do NOT fuse the final reduction into this kernel. R5/R6 showed the
// double-precision last-block tail pushes peak VGPR pressure over the
// launch_bounds(1024,8) 64-reg cap; the allocator then serializes the main
// loop's vector loads down to a 24-VGPR allocation (22us -> 66us).
__global__ __launch_bounds__(EDGE_THREADS, 8) void edge_loss_lds(
    const unsigned* __restrict__ packed_g,
    const float* __restrict__ edge_scores,
    const int*   __restrict__ edge_src,
    const int*   __restrict__ edge_dst,
    const float* __restrict__ adj,
    float*       __restrict__ partial,
    int n_edges, int n_words)
{
    __shared__ unsigned s_packed[PACK_WORDS_MAX]; // 50,048 B
    __shared__ unsigned s_mask[16];
    __shared__ float    s_wsum[EDGE_THREADS / 64];

    const int tid = threadIdx.x;

    if (tid < 16) {
        unsigned m = 0u;
        if (tid < 12) {
            #pragma unroll
            for (int j = 0; j < 12; ++j)
                if (adj[tid * 12 + j] > 0.5f) m |= (1u << j);
        }
        s_mask[tid] = m;
    }
    {
        int nv = n_words >> 2;
        const uint4* p4 = (const uint4*)packed_g;
        for (int i = tid; i < nv; i += EDGE_THREADS) {
            uint4 v = p4[i];
            s_packed[4*i+0] = v.x; s_packed[4*i+1] = v.y;
            s_packed[4*i+2] = v.z; s_packed[4*i+3] = v.w;
        }
        for (int i = (nv << 2) + tid; i < n_words; i += EDGE_THREADS)
            s_packed[i] = packed_g[i];
    }
    __syncthreads();

    const int gtid   = blockIdx.x * EDGE_THREADS + tid;
    const int stride = gridDim.x * EDGE_THREADS;
    const int ngrp   = n_edges >> 2;

    const int4*   srcv = (const int4*)  edge_src;
    const int4*   dstv = (const int4*)  edge_dst;
    const float4* scov = (const float4*)edge_scores;

    float acc_a = 0.0f;   // max(s,0) - y*s terms
    float acc_l = 0.0f;   // log2-domain terms (scale by LN2 at end)

    int g = gtid;
    if (g < ngrp) {
        // explicit 2-deep pipeline keeps the load batch VGPR-resident
        int4   si = srcv[g];
        int4   di = dstv[g];
        float4 sc = scov[g];

        while (true) {
            const int gn = g + stride;
            int4 si_n, di_n; float4 sc_n;
            const bool more = (gn < ngrp);
            if (more) {
                si_n = srcv[gn];
                di_n = dstv[gn];
                sc_n = scov[gn];
            }

            unsigned wa0 = s_packed[si.x >> 3], wa1 = s_packed[si.y >> 3];
            unsigned wa2 = s_packed[si.z >> 3], wa3 = s_packed[si.w >> 3];
            unsigned wb0 = s_packed[di.x >> 3], wb1 = s_packed[di.y >> 3];
            unsigned wb2 = s_packed[di.z >> 3], wb3 = s_packed[di.w >> 3];

            int a0 = (wa0 >> ((si.x & 7) << 2)) & 0xF;
            int a1 = (wa1 >> ((si.y & 7) << 2)) & 0xF;
            int a2 = (wa2 >> ((si.z & 7) << 2)) & 0xF;
            int a3 = (wa3 >> ((si.w & 7) << 2)) & 0xF;
            int b0 = (wb0 >> ((di.x & 7) << 2)) & 0xF;
            int b1 = (wb1 >> ((di.y & 7) << 2)) & 0xF;
            int b2 = (wb2 >> ((di.z & 7) << 2)) & 0xF;
            int b3 = (wb3 >> ((di.w & 7) << 2)) & 0xF;

            unsigned y0 = (s_mask[a0] >> b0) & 1u;
            unsigned y1 = (s_mask[a1] >> b1) & 1u;
            unsigned y2 = (s_mask[a2] >> b2) & 1u;
            unsigned y3 = (s_mask[a3] >> b3) & 1u;

            float s0 = sc.x, s1 = sc.y, s2 = sc.z, s3 = sc.w;

            float t0 = __builtin_amdgcn_exp2f(-fabsf(s0) * LOG2E);
            float t1 = __builtin_amdgcn_exp2f(-fabsf(s1) * LOG2E);
            float t2 = __builtin_amdgcn_exp2f(-fabsf(s2) * LOG2E);
            float t3 = __builtin_amdgcn_exp2f(-fabsf(s3) * LOG2E);

            acc_a += fmaxf(s0, 0.0f) - (y0 ? s0 : 0.0f);
            acc_a += fmaxf(s1, 0.0f) - (y1 ? s1 : 0.0f);
            acc_a += fmaxf(s2, 0.0f) - (y2 ? s2 : 0.0f);
            acc_a += fmaxf(s3, 0.0f) - (y3 ? s3 : 0.0f);

            acc_l += __builtin_amdgcn_logf(1.0f + t0);
            acc_l += __builtin_amdgcn_logf(1.0f + t1);
            acc_l += __builtin_amdgcn_logf(1.0f + t2);
            acc_l += __builtin_amdgcn_logf(1.0f + t3);

            if (!more) break;
            si = si_n; di = di_n; sc = sc_n; g = gn;
        }
    }

    // scalar tail (n_edges not divisible by 4)
    for (int e = (ngrp << 2) + gtid; e < n_edges; e += stride) {
        int n = edge_src[e], m = edge_dst[e];
        int a = (s_packed[n >> 3] >> ((n & 7) << 2)) & 0xF;
        int b = (s_packed[m >> 3] >> ((m & 7) << 2)) & 0xF;
        unsigned y = (s_mask[a] >> b) & 1u;
        float s = edge_scores[e];
        float t = __builtin_amdgcn_exp2f(-fabsf(s) * LOG2E);
        acc_a += fmaxf(s, 0.0f) - (y ? s : 0.0f);
        acc_l += __builtin_amdgcn_logf(1.0f + t);
    }

    float acc = fmaf(LN2, acc_l, acc_a);

    #pragma unroll
    for (int off = 32; off > 0; off >>= 1)
        acc += __shfl_down(acc, off, 64);

    const int wave = tid >> 6;
    const int lane = tid & 63;
    if (lane == 0) s_wsum[wave] = acc;
    __syncthreads();

    if (tid == 0) {
        float b = 0.0f;
        #pragma unroll
        for (int w = 0; w < EDGE_THREADS / 64; ++w) b += s_wsum[w];
        partial[blockIdx.x] = b;
    }
}

// ---------- fallback path ----------
__global__ __launch_bounds__(256) void edge_loss_fallback(
    const int*   __restrict__ node_classes,
    const float* __restrict__ edge_scores,
    const int*   __restrict__ edge_src,
    const int*   __restrict__ edge_dst,
    const float* __restrict__ adj,
    float*       __restrict__ partial,
    int n_edges)
{
    __shared__ unsigned s_mask[16];
    const int tid = threadIdx.x;
    if (tid < 12) {
        unsigned m = 0u;
        for (int j = 0; j < 12; ++j)
            if (adj[tid * 12 + j] > 0.5f) m |= (1u << j);
        s_mask[tid] = m;
    }
    __syncthreads();
    const int gtid   = blockIdx.x * 256 + tid;
    const int stride = gridDim.x * 256;
    float acc = 0.0f;
    for (int e = gtid; e < n_edges; e += stride) {
        int a = node_classes[edge_src[e]];
        int b = node_classes[edge_dst[e]];
        float y = (float)((s_mask[a] >> b) & 1u);
        float s = edge_scores[e];
        float t = __builtin_amdgcn_exp2f(-fabsf(s) * LOG2E);
        acc += fmaxf(s, 0.0f) - s * y + LN2 * __builtin_amdgcn_logf(1.0f + t);
    }
    #pragma unroll
    for (int off = 32; off > 0; off >>= 1)
        acc += __shfl_down(acc, off, 64);
    __shared__ float s_wsum[4];
    const int wave = tid >> 6, lane = tid & 63;
    if (lane == 0) s_wsum[wave] = acc;
    __syncthreads();
    if (tid == 0) {
        float b = 0.0f;
        for (int w = 0; w < 4; ++w) b += s_wsum[w];
        partial[blockIdx.x] = b;
    }
}

__global__ __launch_bounds__(256) void final_reduce(
    const float* __restrict__ partial,
    float*       __restrict__ out,
    int nblk, float inv_n)
{
    const int tid = threadIdx.x;
    double acc = 0.0;
    for (int i = tid; i < nblk; i += 256) acc += (double)partial[i];
    #pragma unroll
    for (int off = 32; off > 0; off >>= 1)
        acc += __shfl_down(acc, off, 64);
    __shared__ double s_wsum[4];
    const int wave = tid >> 6, lane = tid & 63;
    if (lane == 0) s_wsum[wave] = acc;
    __syncthreads();
    if (tid == 0) {
        double t = s_wsum[0] + s_wsum[1] + s_wsum[2] + s_wsum[3];
        out[0] = (float)(t * (double)inv_n);
    }
}

extern "C" void kernel_launch(void* const* d_in, const int* in_sizes, int n_in,
                              void* d_out, int out_size, void* d_ws, size_t ws_size,
                              hipStream_t stream) {
    const int*   node_classes = (const int*)  d_in[0];
    const float* edge_scores  = (const float*)d_in[1];
    const int*   edge_indices = (const int*)  d_in[2];
    const float* adj          = (const float*)d_in[3];

    const int n_nodes = in_sizes[0];
    const int n_edges = in_sizes[1];
    const int n_words = (n_nodes + 7) >> 3;

    const int* edge_src = edge_indices;
    const int* edge_dst = edge_indices + n_edges;

    char* ws = (char*)d_ws;
    float*    partial = (float*)   (ws + WS_PART_OFF);
    unsigned* packed  = (unsigned*)(ws + WS_PACK_OFF);
    float* out = (float*)d_out;

    const size_t needed = (size_t)WS_PACK_OFF + (size_t)n_words * 4u;

    if (ws_size >= needed && n_words <= PACK_WORDS_MAX) {
        int pack_blocks = (n_words + 255) / 256;
        pack_classes<<<pack_blocks, 256, 0, stream>>>(
            node_classes, packed, n_nodes, n_words);
        edge_loss_lds<<<EDGE_BLOCKS, EDGE_THREADS, 0, stream>>>(
            packed, edge_scores, edge_src, edge_dst, adj, partial,
            n_edges, n_words);
        final_reduce<<<1, 256, 0, stream>>>(partial, out, EDGE_BLOCKS,
                                            1.0f / (float)n_edges);
    } else {
        edge_loss_fallback<<<2048, 256, 0, stream>>>(
            node_classes, edge_scores, edge_src, edge_dst, adj, partial, n_edges);
        final_reduce<<<1, 256, 0, stream>>>(partial, out, 2048,
                                            1.0f / (float)n_edges);
    }
}